// Round 6
// baseline (659.976 us; speedup 1.0000x reference)
//
#include <hip/hip_runtime.h>
#include <hip/hip_bf16.h>
#include <stdint.h>

#define L_ 25
#define E_ 64
#define H_ 8
#define B_ 1000
#define S_ 512
#define GQ 4                       // batch elements per block
#define NCELL (L_ * GQ)            // 100 cells per block
#define TPBR (NCELL * 8)           // 800 threads, thread = (cell, j)
#define NSUPER (S_ / 2 + L_ - 1)   // 280 supersteps (2 timesteps each)
#define XG 20                      // per-cell stride xbuf (words), 80B: b128-aligned

typedef float v4f __attribute__((ext_vector_type(4)));

__device__ __forceinline__ float ulo(uint32_t u) { return __uint_as_float(u << 16); }
__device__ __forceinline__ float uhi(uint32_t u) { return __uint_as_float(u & 0xffff0000u); }

__device__ __forceinline__ float toF(float v) { return v; }
__device__ __forceinline__ float toF(__hip_bfloat16 v) { return __bfloat162float(v); }
__device__ __forceinline__ void stP(float* p, float v) { *p = v; }
__device__ __forceinline__ void stP(__hip_bfloat16* p, float v) { *p = __float2bfloat16(v); }

// load 8 consecutive elements as two v4f (SSA vectors, never memory)
__device__ __forceinline__ void loadrow(const float* p, v4f& a, v4f& b) {
  a = ((const v4f*)p)[0];
  b = ((const v4f*)p)[1];
}
__device__ __forceinline__ void loadrow(const __hip_bfloat16* p, v4f& a, v4f& b) {
  const uint4 v = *(const uint4*)p;
  a = (v4f){ulo(v.x), uhi(v.x), ulo(v.y), uhi(v.y)};
  b = (v4f){ulo(v.z), uhi(v.z), ulo(v.w), uhi(v.w)};
}

__device__ __forceinline__ float sigmo(float x) {
  x = fminf(fmaxf(x, -30.f), 30.f);
  return 1.f / (1.f + __expf(-x));
}
__device__ __forceinline__ float tanh_(float x) {
  x = fminf(fmaxf(x, -15.f), 15.f);
  const float e = __expf(-2.f * x);
  return (1.f - e) / (1.f + e);
}

// ---- cross-lane XOR exchange within 8-lane cells ----
template <int CTRL>
__device__ __forceinline__ float qp(float v) {  // quad_perm (VALU DPP)
  return __int_as_float(__builtin_amdgcn_mov_dpp(__float_as_int(v), CTRL, 0xF, 0xF, true));
}
__device__ __forceinline__ float swz4(float v) {  // lane ^= 4 (DS pipe)
  return __int_as_float(__builtin_amdgcn_ds_swizzle(__float_as_int(v), 0x101F));
}

// one GRU cell update, fully scalar (no arrays). Weight vectors are
// XOR-permuted columns: element k corresponds to row (j^k).
__device__ __forceinline__ float cellstep(float hown, float az, float ar, float ah,
                                          v4f whzA, v4f whzB, v4f whrA, v4f whrB,
                                          v4f wrhA, v4f wrhB) {
  const float h0 = hown;
  const float h1 = qp<0xB1>(h0), h2 = qp<0x4E>(h0), h3 = qp<0x1B>(h0);
  const float h4 = swz4(h0);
  const float h5 = qp<0xB1>(h4), h6 = qp<0x4E>(h4), h7 = qp<0x1B>(h4);
  az = fmaf(h0, whzA[0], az); az = fmaf(h1, whzA[1], az);
  az = fmaf(h2, whzA[2], az); az = fmaf(h3, whzA[3], az);
  az = fmaf(h4, whzB[0], az); az = fmaf(h5, whzB[1], az);
  az = fmaf(h6, whzB[2], az); az = fmaf(h7, whzB[3], az);
  ar = fmaf(h0, whrA[0], ar); ar = fmaf(h1, whrA[1], ar);
  ar = fmaf(h2, whrA[2], ar); ar = fmaf(h3, whrA[3], ar);
  ar = fmaf(h4, whrB[0], ar); ar = fmaf(h5, whrB[1], ar);
  ar = fmaf(h6, whrB[2], ar); ar = fmaf(h7, whrB[3], ar);
  const float z = sigmo(az);
  const float r = sigmo(ar);
  const float g0 = hown * r;
  const float g1 = qp<0xB1>(g0), g2 = qp<0x4E>(g0), g3 = qp<0x1B>(g0);
  const float g4 = swz4(g0);
  const float g5 = qp<0xB1>(g4), g6 = qp<0x4E>(g4), g7 = qp<0x1B>(g4);
  ah = fmaf(g0, wrhA[0], ah); ah = fmaf(g1, wrhA[1], ah);
  ah = fmaf(g2, wrhA[2], ah); ah = fmaf(g3, wrhA[3], ah);
  ah = fmaf(g4, wrhB[0], ah); ah = fmaf(g5, wrhB[1], ah);
  ah = fmaf(g6, wrhB[2], ah); ah = fmaf(g7, wrhB[3], ah);
  return fmaf(z, tanh_(ah) - hown, hown);
}

// ---------------------------------------------------------------------------
// Kernel 0: dtype probe (fp32 vs bf16 inputs).
// ---------------------------------------------------------------------------
__global__ void gru_detect(const unsigned short* __restrict__ u16, int* __restrict__ flag) {
  const int i = threadIdx.x;  // 64 threads
  float m = 0.f;
#pragma unroll
  for (int k = 0; k < 4; ++k) {
    const uint32_t u = u16[i * 4 + k];
    float v = fabsf(__uint_as_float(u << 16));
    if (!(v < 1e30f)) v = 1e30f;
    m = fmaxf(m, v);
  }
#pragma unroll
  for (int off = 32; off; off >>= 1) m = fmaxf(m, __shfl_down(m, off, 64));
  if (i == 0) *flag = (m > 2.0f) ? 0 : 1;  // 0 = fp32 inputs, 1 = bf16 inputs
}

// ---------------------------------------------------------------------------
// Kernel 1: layer-0 x-projections. No LDS: weight rows are wave-uniform
// global reads (L1-broadcast / scalarizable). 4 tokens/thread, named v4f
// accumulators. pre layout: [(b*S+t)*24 + j*3 + gate].
// ---------------------------------------------------------------------------
#define DECLP(p) v4f Za##p = {0,0,0,0}, Zb##p = {0,0,0,0}, Ra##p = {0,0,0,0}, \
                     Rb##p = {0,0,0,0}, Ha##p = {0,0,0,0}, Hb##p = {0,0,0,0}
#define FMAP(p, e) { Za##p += (e) * za; Zb##p += (e) * zb; Ra##p += (e) * ra; \
                     Rb##p += (e) * rb; Ha##p += (e) * ha; Hb##p += (e) * hb; }
#define STOREP(p, pos) { PT* o = pre + (size_t)(pos) * 24;                     \
    stP(o+0,  Za##p[0]); stP(o+1,  Ra##p[0]); stP(o+2,  Ha##p[0]);             \
    stP(o+3,  Za##p[1]); stP(o+4,  Ra##p[1]); stP(o+5,  Ha##p[1]);             \
    stP(o+6,  Za##p[2]); stP(o+7,  Ra##p[2]); stP(o+8,  Ha##p[2]);             \
    stP(o+9,  Za##p[3]); stP(o+10, Ra##p[3]); stP(o+11, Ha##p[3]);             \
    stP(o+12, Zb##p[0]); stP(o+13, Rb##p[0]); stP(o+14, Hb##p[0]);             \
    stP(o+15, Zb##p[1]); stP(o+16, Rb##p[1]); stP(o+17, Hb##p[1]);             \
    stP(o+18, Zb##p[2]); stP(o+19, Rb##p[2]); stP(o+20, Hb##p[2]);             \
    stP(o+21, Zb##p[3]); stP(o+22, Rb##p[3]); stP(o+23, Hb##p[3]); }

template <typename T, typename PT>
__global__ __launch_bounds__(256, 2) void gru_pre(
    const int* __restrict__ flag, int want,
    const int* __restrict__ x, const T* __restrict__ emb,
    const T* __restrict__ Wz, const T* __restrict__ Wr,
    const T* __restrict__ Wh, PT* __restrict__ pre) {
  if (*flag != want) return;
  const int pos0 = (blockIdx.x * 256 + threadIdx.x) * 4;  // 4 tokens/thread
  const int4 t4 = *(const int4*)(x + pos0);

  DECLP(0); DECLP(1); DECLP(2); DECLP(3);

  for (int kb = 0; kb < 8; ++kb) {
    v4f eA0, eB0, eA1, eB1, eA2, eB2, eA3, eB3;
    loadrow(emb + (size_t)t4.x * E_ + kb * 8, eA0, eB0);
    loadrow(emb + (size_t)t4.y * E_ + kb * 8, eA1, eB1);
    loadrow(emb + (size_t)t4.z * E_ + kb * 8, eA2, eB2);
    loadrow(emb + (size_t)t4.w * E_ + kb * 8, eA3, eB3);
#pragma unroll
    for (int k8 = 0; k8 < 8; ++k8) {
      v4f za, zb, ra, rb, ha, hb;
      const int row = (kb * 8 + k8) * 8;  // wave-uniform
      loadrow(Wz + row, za, zb);
      loadrow(Wr + row, ra, rb);
      loadrow(Wh + row, ha, hb);
      const float e0 = (k8 < 4) ? eA0[k8 & 3] : eB0[k8 & 3];
      const float e1 = (k8 < 4) ? eA1[k8 & 3] : eB1[k8 & 3];
      const float e2 = (k8 < 4) ? eA2[k8 & 3] : eB2[k8 & 3];
      const float e3 = (k8 < 4) ? eA3[k8 & 3] : eB3[k8 & 3];
      FMAP(0, e0); FMAP(1, e1); FMAP(2, e2); FMAP(3, e3);
    }
  }
  STOREP(0, pos0 + 0); STOREP(1, pos0 + 1);
  STOREP(2, pos0 + 2); STOREP(3, pos0 + 3);
}

// ---------------------------------------------------------------------------
// Kernel 2: pipelined recurrence. Superstep s: layer l does t = 2(s-l), +1.
// h / h*r via DPP+swizzle XOR tours (no LDS); weights as pinned v4f SSA
// tuples (scratch impossible); only the inter-layer x handoff uses LDS.
// ---------------------------------------------------------------------------
template <typename T, typename PT>
__global__ __launch_bounds__(TPBR, 3) void gru_rec(
    const int* __restrict__ flag, int want,
    const PT* __restrict__ pre,
    const T* __restrict__ Whz0, const T* __restrict__ bz0,
    const T* __restrict__ Whr0, const T* __restrict__ br0,
    const T* __restrict__ WrH0, const T* __restrict__ bH0,
    const T* __restrict__ Wxz, const T* __restrict__ Whz,
    const T* __restrict__ bz, const T* __restrict__ Wxr,
    const T* __restrict__ Whr, const T* __restrict__ br,
    const T* __restrict__ WxH, const T* __restrict__ WrH,
    const T* __restrict__ bH, const T* __restrict__ Why,
    const T* __restrict__ by, T* __restrict__ out) {
  if (*flag != want) return;
  __shared__ __align__(16) float xbuf[2 * NCELL * XG];

  const int tid = threadIdx.x;
  const int gi = tid >> 3;   // cell = l*GQ + g, 0..99
  const int j = tid & 7;
  const int l = gi >> 2;
  const int g = gi & 3;
  const int b = blockIdx.x * GQ + g;

  // ---- weights as v4f SSA values (element k = row (j^k) for h-side) ----
  v4f wxzA = {0,0,0,0}, wxzB = {0,0,0,0}, wxrA = {0,0,0,0}, wxrB = {0,0,0,0};
  v4f wxhA = {0,0,0,0}, wxhB = {0,0,0,0};
  v4f whzA, whzB, whrA, whrB, wrhA, wrhB, bias;
  if (l == 0) {
#pragma unroll
    for (int k = 0; k < 4; ++k) {
      const int rkA = (j ^ k) * 8 + j;
      const int rkB = (j ^ (k + 4)) * 8 + j;
      whzA[k] = toF(Whz0[rkA]); whzB[k] = toF(Whz0[rkB]);
      whrA[k] = toF(Whr0[rkA]); whrB[k] = toF(Whr0[rkB]);
      wrhA[k] = toF(WrH0[rkA]); wrhB[k] = toF(WrH0[rkB]);
    }
    bias = (v4f){toF(bz0[j]), toF(br0[j]), toF(bH0[j]), 0.f};
  } else {
    const int base = (l - 1) * 64;
#pragma unroll
    for (int k = 0; k < 4; ++k) {
      const int nkA = base + k * 8 + j;
      const int nkB = base + (k + 4) * 8 + j;
      const int rkA = base + (j ^ k) * 8 + j;
      const int rkB = base + (j ^ (k + 4)) * 8 + j;
      wxzA[k] = toF(Wxz[nkA]); wxzB[k] = toF(Wxz[nkB]);
      wxrA[k] = toF(Wxr[nkA]); wxrB[k] = toF(Wxr[nkB]);
      wxhA[k] = toF(WxH[nkA]); wxhB[k] = toF(WxH[nkB]);
      whzA[k] = toF(Whz[rkA]); whzB[k] = toF(Whz[rkB]);
      whrA[k] = toF(Whr[rkA]); whrB[k] = toF(Whr[rkB]);
      wrhA[k] = toF(WrH[rkA]); wrhB[k] = toF(WrH[rkB]);
    }
    bias = (v4f){toF(bz[(l - 1) * 8 + j]), toF(br[(l - 1) * 8 + j]),
                 toF(bH[(l - 1) * 8 + j]), 0.f};
  }

  // layer-0 precomputed x-projection ([j*3+gate] layout: contiguous per slot)
  const PT* ppr = pre + (size_t)b * (S_ * 24) + j * 3;
  float cz0 = 0.f, cr0 = 0.f, ch0 = 0.f, cz1 = 0.f, cr1 = 0.f, ch1 = 0.f;
  if (l == 0) {
    cz0 = toF(ppr[0]);  cr0 = toF(ppr[1]);  ch0 = toF(ppr[2]);
    cz1 = toF(ppr[24]); cr1 = toF(ppr[25]); ch1 = toF(ppr[26]);
  }

  const int gp = (gi >= GQ) ? (gi - GQ) * XG : 0;
  const float* xpe = xbuf + NCELL * XG + gp;  // read when s even
  const float* xpo = xbuf + gp;               // read when s odd
  float* xce = xbuf + gi * XG;                // write when s even
  float* xco = xbuf + NCELL * XG + gi * XG;   // write when s odd

  float hown = 0.f;

  __syncthreads();

  for (int s = 0; s < NSUPER; ++s) {
    // black-box write of all weight tuples: cannot be remat'd from memory,
    // and they were never memory objects -> guaranteed VGPR residency.
    asm volatile("" : "+v"(wxzA), "+v"(wxzB), "+v"(wxrA), "+v"(wxrB),
                      "+v"(wxhA), "+v"(wxhB), "+v"(whzA), "+v"(whzB),
                      "+v"(whrA), "+v"(whrB), "+v"(wrhA), "+v"(wrhB),
                      "+v"(bias));

    const unsigned rel = (unsigned)(s - l);
    if (rel < (unsigned)(S_ / 2)) {
      const float* xp = (s & 1) ? xpo : xpe;
      float* xc = (s & 1) ? xco : xce;

      float az0, ar0, ah0, az1, ar1, ah1;
      if (l == 0) {
        az0 = bias[0] + cz0; ar0 = bias[1] + cr0; ah0 = bias[2] + ch0;
        az1 = bias[0] + cz1; ar1 = bias[1] + cr1; ah1 = bias[2] + ch1;
        if (rel + 1 < (unsigned)(S_ / 2)) {  // prefetch next superstep
          const PT* pn = ppr + (rel + 1) * 48;
          cz0 = toF(pn[0]);  cr0 = toF(pn[1]);  ch0 = toF(pn[2]);
          cz1 = toF(pn[24]); cr1 = toF(pn[25]); ch1 = toF(pn[26]);
        }
      } else {
        // x pairs: word 2k = slot0[k], word 2k+1 = slot1[k]
        const v4f q0 = ((const v4f*)xp)[0];
        const v4f q1 = ((const v4f*)xp)[1];
        const v4f q2 = ((const v4f*)xp)[2];
        const v4f q3 = ((const v4f*)xp)[3];
        az0 = bias[0]; ar0 = bias[1]; ah0 = bias[2];
        az1 = bias[0]; ar1 = bias[1]; ah1 = bias[2];
        az0 = fmaf(q0[0], wxzA[0], az0); az1 = fmaf(q0[1], wxzA[0], az1);
        ar0 = fmaf(q0[0], wxrA[0], ar0); ar1 = fmaf(q0[1], wxrA[0], ar1);
        ah0 = fmaf(q0[0], wxhA[0], ah0); ah1 = fmaf(q0[1], wxhA[0], ah1);
        az0 = fmaf(q0[2], wxzA[1], az0); az1 = fmaf(q0[3], wxzA[1], az1);
        ar0 = fmaf(q0[2], wxrA[1], ar0); ar1 = fmaf(q0[3], wxrA[1], ar1);
        ah0 = fmaf(q0[2], wxhA[1], ah0); ah1 = fmaf(q0[3], wxhA[1], ah1);
        az0 = fmaf(q1[0], wxzA[2], az0); az1 = fmaf(q1[1], wxzA[2], az1);
        ar0 = fmaf(q1[0], wxrA[2], ar0); ar1 = fmaf(q1[1], wxrA[2], ar1);
        ah0 = fmaf(q1[0], wxhA[2], ah0); ah1 = fmaf(q1[1], wxhA[2], ah1);
        az0 = fmaf(q1[2], wxzA[3], az0); az1 = fmaf(q1[3], wxzA[3], az1);
        ar0 = fmaf(q1[2], wxrA[3], ar0); ar1 = fmaf(q1[3], wxrA[3], ar1);
        ah0 = fmaf(q1[2], wxhA[3], ah0); ah1 = fmaf(q1[3], wxhA[3], ah1);
        az0 = fmaf(q2[0], wxzB[0], az0); az1 = fmaf(q2[1], wxzB[0], az1);
        ar0 = fmaf(q2[0], wxrB[0], ar0); ar1 = fmaf(q2[1], wxrB[0], ar1);
        ah0 = fmaf(q2[0], wxhB[0], ah0); ah1 = fmaf(q2[1], wxhB[0], ah1);
        az0 = fmaf(q2[2], wxzB[1], az0); az1 = fmaf(q2[3], wxzB[1], az1);
        ar0 = fmaf(q2[2], wxrB[1], ar0); ar1 = fmaf(q2[3], wxrB[1], ar1);
        ah0 = fmaf(q2[2], wxhB[1], ah0); ah1 = fmaf(q2[3], wxhB[1], ah1);
        az0 = fmaf(q3[0], wxzB[2], az0); az1 = fmaf(q3[1], wxzB[2], az1);
        ar0 = fmaf(q3[0], wxrB[2], ar0); ar1 = fmaf(q3[1], wxrB[2], ar1);
        ah0 = fmaf(q3[0], wxhB[2], ah0); ah1 = fmaf(q3[1], wxhB[2], ah1);
        az0 = fmaf(q3[2], wxzB[3], az0); az1 = fmaf(q3[3], wxzB[3], az1);
        ar0 = fmaf(q3[2], wxrB[3], ar0); ar1 = fmaf(q3[3], wxrB[3], ar1);
        ah0 = fmaf(q3[2], wxhB[3], ah0); ah1 = fmaf(q3[3], wxhB[3], ah1);
      }

      const float hn0 = cellstep(hown, az0, ar0, ah0, whzA, whzB, whrA, whrB, wrhA, wrhB);
      const float hn1 = cellstep(hn0, az1, ar1, ah1, whzA, whzB, whrA, whrB, wrhA, wrhB);
      *(float2*)(xc + 2 * j) = make_float2(hn0, hn1);  // ds_write_b64
      hown = hn1;
    }
    __syncthreads();
  }

  // ---- epilogue: h_last and logits (lane-reduced, no LDS) ----
  stP(out + B_ + (l * B_ + b) * H_ + j, hown);
  if (l == L_ - 1) {
    float sum = hown * toF(Why[j]);
    sum += qp<0xB1>(sum);
    sum += qp<0x4E>(sum);
    sum += swz4(sum);
    if (j == 0) stP(out + b, sum + toF(by[0]));
  }
}

// ---------------------------------------------------------------------------
template <typename T, typename PT>
static void launch_mode(const int* flag, int want, void* const* d_in, PT* pre,
                        T* out, hipStream_t stream) {
  const int* x = (const int*)d_in[0];
  const T* emb = (const T*)d_in[1];
  const T* Wxz0 = (const T*)d_in[2];
  const T* Whz0 = (const T*)d_in[3];
  const T* bz0 = (const T*)d_in[4];
  const T* Wxr0 = (const T*)d_in[5];
  const T* Whr0 = (const T*)d_in[6];
  const T* br0 = (const T*)d_in[7];
  const T* WxH0 = (const T*)d_in[8];
  const T* WrH0 = (const T*)d_in[9];
  const T* bH0 = (const T*)d_in[10];
  const T* Wxz = (const T*)d_in[11];
  const T* Whz = (const T*)d_in[12];
  const T* bz = (const T*)d_in[13];
  const T* Wxr = (const T*)d_in[14];
  const T* Whr = (const T*)d_in[15];
  const T* br = (const T*)d_in[16];
  const T* WxH = (const T*)d_in[17];
  const T* WrH = (const T*)d_in[18];
  const T* bH = (const T*)d_in[19];
  const T* Why = (const T*)d_in[20];
  const T* by = (const T*)d_in[21];

  gru_pre<T, PT><<<B_ * S_ / 4 / 256, 256, 0, stream>>>(flag, want, x, emb,
                                                        Wxz0, Wxr0, WxH0, pre);
  gru_rec<T, PT><<<B_ / GQ, TPBR, 0, stream>>>(
      flag, want, pre, Whz0, bz0, Whr0, br0, WrH0, bH0, Wxz, Whz, bz, Wxr, Whr,
      br, WxH, WrH, bH, Why, by, out);
}

extern "C" void kernel_launch(void* const* d_in, const int* in_sizes, int n_in,
                              void* d_out, int out_size, void* d_ws, size_t ws_size,
                              hipStream_t stream) {
  int* flag = (int*)d_ws;
  char* preMem = (char*)d_ws + 256;
  const size_t needF = (size_t)B_ * S_ * 24 * sizeof(float) + 256;

  gru_detect<<<1, 64, 0, stream>>>((const unsigned short*)d_in[1], flag);

  if (ws_size >= needF) {
    float* pre = (float*)preMem;
    launch_mode<float, float>(flag, 0, d_in, pre, (float*)d_out, stream);
    launch_mode<__hip_bfloat16, float>(flag, 1, d_in, pre, (__hip_bfloat16*)d_out, stream);
  } else {
    __hip_bfloat16* pre = (__hip_bfloat16*)preMem;
    launch_mode<float, __hip_bfloat16>(flag, 0, d_in, pre, (float*)d_out, stream);
    launch_mode<__hip_bfloat16, __hip_bfloat16>(flag, 1, d_in, pre, (__hip_bfloat16*)d_out, stream);
  }
}